// Round 1
// 655.275 us; speedup vs baseline: 1.0774x; 1.0774x over previous
//
#include <hip/hip_runtime.h>
#include <hip/hip_bf16.h>
#include <stdint.h>

// Problem constants
#define MM   32768   // B*S
#define FFD  1024    // F
#define NQKV 3072    // 3*F

typedef __bf16 bf16x8 __attribute__((ext_vector_type(8)));
typedef float  f32x4  __attribute__((ext_vector_type(4)));

__device__ __forceinline__ unsigned short f2bf_bits(float f){
  __hip_bfloat16 h = __float2bfloat16(f);
  unsigned short u;
  __builtin_memcpy(&u, &h, 2);
  return u;
}

__device__ __forceinline__ void gld16(const void* g, void* l){
  const unsigned int* gu = (const unsigned int*)g;
  unsigned int* lu = (unsigned int*)l;
  __builtin_amdgcn_global_load_lds(
      (const __attribute__((address_space(1))) unsigned int*)gu,
      (__attribute__((address_space(3))) unsigned int*)lu,
      16, 0, 0);
}

// Raw barrier (no vmcnt(0) auto-drain like __syncthreads) + compiler memory fence
#define BARRIER() do { asm volatile("" ::: "memory"); \
                       __builtin_amdgcn_s_barrier();  \
                       asm volatile("" ::: "memory"); } while(0)

// ---------- convert fp32 -> bf16, 4 elems/thread ----------
__global__ __launch_bounds__(256) void k_convert_bf16(const float* __restrict__ in,
                                                      unsigned short* __restrict__ out,
                                                      int n4){
  int i = blockIdx.x * 256 + threadIdx.x;
  if (i >= n4) return;
  float4 v = ((const float4*)in)[i];
  ushort4 r;
  r.x = f2bf_bits(v.x); r.y = f2bf_bits(v.y);
  r.z = f2bf_bits(v.z); r.w = f2bf_bits(v.w);
  ((ushort4*)out)[i] = r;
}

// ---------- transpose-convert: out(N x K bf16) = in(K x N fp32)^T ----------
__global__ __launch_bounds__(256) void k_transpose_bf16(const float* __restrict__ in,
                                                        unsigned short* __restrict__ out,
                                                        int rows, int cols){
  __shared__ float tile[32][33];
  int bc = blockIdx.x * 32, br = blockIdx.y * 32;
  int tx = threadIdx.x, ty = threadIdx.y;
  #pragma unroll
  for (int j = 0; j < 32; j += 8)
    tile[ty + j][tx] = in[(size_t)(br + ty + j) * cols + bc + tx];
  __syncthreads();
  #pragma unroll
  for (int j = 0; j < 32; j += 8)
    out[(size_t)(bc + ty + j) * rows + br + tx] = f2bf_bits(tile[tx][ty + j]);
}

// ---------- bf16 MFMA GEMM: C(MxN) = A(MxK) * Bt(NxK)^T + bias ----------
// 256x256 tile, BK=32, 512 threads (8 waves, 2Mx4N), 16x16x32 MFMA.
// Ring-4 LDS (4 x 32KB = 128 KiB), staged 3 K-tiles ahead via global_load_lds,
// counted s_waitcnt vmcnt(8) at tile boundaries (never 0 in steady state),
// 2 phases per tile {4-8 ds_read_b128 | 2 staging issues | barrier | 16 MFMA
// under setprio(1) | barrier}, XOR bank swizzle byte^=((row>>1)&3)<<4 applied
// on reads and pre-inverted on the per-lane GLOBAL source (LDS dest stays
// linear as global_load_lds requires).
template <bool BF16OUT>
__global__ __launch_bounds__(512, 2) void k_gemm_bt(
    const unsigned short* __restrict__ A,
    const unsigned short* __restrict__ Bt,
    const float* __restrict__ b0, const float* __restrict__ b1, const float* __restrict__ b2,
    void* __restrict__ Cout, int M, int N, int K)
{
  __shared__ alignas(16) char smem[131072];

  const int tid  = threadIdx.x;
  const int lane = tid & 63;
  const int wave = tid >> 6;
  const int wr = wave >> 2, wc = wave & 3;       // 2 x 4 wave grid
  const int quad = lane >> 4, lrow = lane & 15;
  const int sa = ((lrow >> 1) & 3) << 4;         // read-side XOR swizzle bits

  // XCD-aware bijective block swizzle (both launch grids are multiples of 8)
  const int nwgx = gridDim.x;
  int nwg = nwgx * gridDim.y;
  int bid = blockIdx.y * nwgx + blockIdx.x;
  int cpx = nwg >> 3;
  int nid = (bid & 7) * cpx + (bid >> 3);
  int by = nid / nwgx;
  int bx = nid - by * nwgx;

  const long rowBase = (long)by * 256;
  const long colBase = (long)bx * 256;

  f32x4 acc[8][4];
  #pragma unroll
  for (int i = 0; i < 8; i++)
    #pragma unroll
    for (int j = 0; j < 4; j++)
      acc[i][j] = (f32x4){0.f, 0.f, 0.f, 0.f};

  // staging: thread t covers row (t>>2) of a 128-row half, 16B chunk (t&3),
  // with the global column pre-swizzled so linear LDS + swizzled reads match.
  const int swz8 = 8 * ((tid & 3) ^ ((tid >> 3) & 3));
  const unsigned short* gA = A  + (rowBase + (tid >> 2)) * (long)K + swz8;
  const unsigned short* gB = Bt + (colBase + (tid >> 2)) * (long)K + swz8;
  const long hstep = 128L * K;   // 128 rows, in elements

  const int nk = K >> 5;         // number of 32-wide K tiles (K=1024 -> 32)

  // prologue: stage tiles 0..2 into ring slots 0..2 (12 loads/thread)
  #pragma unroll
  for (int tt = 0; tt < 3; ++tt){
    char* nb = smem + tt * 32768;
    gld16(gA + tt * 32,         nb +         tid * 16);
    gld16(gA + tt * 32 + hstep, nb +  8192 + tid * 16);
    gld16(gB + tt * 32,         nb + 16384 + tid * 16);
    gld16(gB + tt * 32 + hstep, nb + 24576 + tid * 16);
  }
  asm volatile("s_waitcnt vmcnt(8)" ::: "memory");   // tile 0 landed
  BARRIER();

  for (int t = 0; t < nk; ++t){
    char* buf = smem + (t & 3) * 32768;
    char* nb  = smem + ((t + 3) & 3) * 32768;
    const unsigned short* sA = gA + (long)(t + 3) * 32;
    const unsigned short* sB = gB + (long)(t + 3) * 32;
    const bool st = (t < nk - 3);

    bf16x8 bfr[4];
    #pragma unroll
    for (int p = 0; p < 2; ++p){
      // ds-load this phase's A fragments (M-half p): rows wr*128 + p*64 + f*16 + lrow
      bf16x8 af[4];
      const char* ab = buf + wr * 8192 + p * 4096 + lrow * 64 + ((quad * 16) ^ sa);
      #pragma unroll
      for (int f = 0; f < 4; ++f)
        af[f] = *(const bf16x8*)(ab + f * 1024);
      if (p == 0){
        // B fragments once per tile: rows wc*64 + n*16 + lrow
        const char* bb = buf + 16384 + wc * 4096 + lrow * 64 + ((quad * 16) ^ sa);
        #pragma unroll
        for (int n = 0; n < 4; ++n)
          bfr[n] = *(const bf16x8*)(bb + n * 1024);
        if (st){   // stage A halves of tile t+3
          gld16(sA,         nb +        tid * 16);
          gld16(sA + hstep, nb + 8192 + tid * 16);
        }
      } else {
        if (st){   // stage B halves of tile t+3
          gld16(sB,         nb + 16384 + tid * 16);
          gld16(sB + hstep, nb + 24576 + tid * 16);
        }
      }
      BARRIER();
      __builtin_amdgcn_s_setprio(1);
      #pragma unroll
      for (int f = 0; f < 4; ++f)
        #pragma unroll
        for (int n = 0; n < 4; ++n)
          acc[p * 4 + f][n] =
              __builtin_amdgcn_mfma_f32_16x16x32_bf16(af[f], bfr[n], acc[p * 4 + f][n], 0, 0, 0);
      __builtin_amdgcn_s_setprio(0);
      if (p == 1){
        // counted wait: tiles t+2,t+3 (8 loads) stay in flight; t+1 certified landed
        if (st)               asm volatile("s_waitcnt vmcnt(8)" ::: "memory");
        else if (t == nk - 3) asm volatile("s_waitcnt vmcnt(4)" ::: "memory");
        else if (t == nk - 2) asm volatile("s_waitcnt vmcnt(0)" ::: "memory");
      }
      BARRIER();
    }
  }

  // epilogue: C/D layout col = lane&15, row-in-frag = quad*4 + r
  #pragma unroll
  for (int n = 0; n < 4; ++n){
    long col = colBase + wc * 64 + n * 16 + lrow;
    const float* bp = (col < 1024) ? b0 : ((col < 2048) ? b1 : b2);
    float bias = bp[col & 1023];
    #pragma unroll
    for (int m = 0; m < 8; ++m){
      long row0 = rowBase + wr * 128 + (m >> 2) * 64 + (m & 3) * 16 + quad * 4;
      #pragma unroll
      for (int r = 0; r < 4; ++r){
        float v = acc[m][n][r] + bias;
        if constexpr (BF16OUT)
          ((unsigned short*)Cout)[(row0 + r) * (long)N + col] = f2bf_bits(v);
        else
          ((float*)Cout)[(row0 + r) * (long)N + col] = v;
      }
    }
  }
}

// ---------- per-position head-attention via MFMA ----------
// One wave per position (4/block). qkv row = [Q(1024)|K(1024)|V(1024)] bf16,
// each matrix [head][d] 16x64. scores = Q K^T / 8 (2x mfma 16x16x32),
// softmax over key-head axis, out = P V (4x mfma with K=32, upper 16 zero-pad).
__global__ __launch_bounds__(256) void k_attention(const unsigned short* __restrict__ qkv,
                                                   unsigned short* __restrict__ aout){
  constexpr int QOFF = 0;            // [16][72] = 1152
  constexpr int KOFF = 1152;         // [16][72] = 1152
  constexpr int VOFF = 2304;         // [64][40] = 2560
  constexpr int POFF = 4864;         // [16][40] = 640
  constexpr int PER  = 5504;         // ushorts per wave
  __shared__ unsigned short smem[4 * PER];

  const int lane = threadIdx.x & 63;
  const int wave = threadIdx.x >> 6;
  const int pos  = blockIdx.x * 4 + wave;
  const int quad = lane >> 4, lidx = lane & 15;

  unsigned short* base = smem + wave * PER;
  unsigned short* Qb = base + QOFF;
  unsigned short* Kb = base + KOFF;
  unsigned short* Vt = base + VOFF;
  unsigned short* Pb = base + POFF;

  {
    uint4 z = {0u, 0u, 0u, 0u};
    *(uint4*)(Vt + lane * 40 + 16) = z;
    *(uint4*)(Vt + lane * 40 + 24) = z;
    *(uint2*)(Pb + (lane >> 2) * 40 + 16 + (lane & 3) * 4) = make_uint2(0u, 0u);
  }

  const unsigned short* src = qkv + (size_t)pos * 3072;
  #pragma unroll
  for (int i = 0; i < 6; i++){
    int c = i * 64 + lane;
    uint4 u = *(const uint4*)(src + c * 8);
    if (i < 4){
      unsigned short* mb = (c < 128) ? Qb : Kb;
      int cc = c & 127;
      *(uint4*)(mb + (cc >> 3) * 72 + (cc & 7) * 8) = u;
    } else {
      int cv = c - 256;
      int g = cv >> 3, d0 = (cv & 7) * 8;
      const unsigned short* us = (const unsigned short*)&u;
      #pragma unroll
      for (int t = 0; t < 8; t++) Vt[(d0 + t) * 40 + g] = us[t];
    }
  }
  __syncthreads();

  f32x4 s = (f32x4){0.f, 0.f, 0.f, 0.f};
  #pragma unroll
  for (int kk = 0; kk < 2; kk++){
    bf16x8 a = *(const bf16x8*)(Qb + lidx * 72 + kk * 32 + quad * 8);
    bf16x8 b = *(const bf16x8*)(Kb + lidx * 72 + kk * 32 + quad * 8);
    s = __builtin_amdgcn_mfma_f32_16x16x32_bf16(a, b, s, 0, 0, 0);
  }

  #pragma unroll
  for (int r = 0; r < 4; r++){
    float v = s[r] * 0.125f;
    float m = v;
    m = fmaxf(m, __shfl_xor(m, 1));
    m = fmaxf(m, __shfl_xor(m, 2));
    m = fmaxf(m, __shfl_xor(m, 4));
    m = fmaxf(m, __shfl_xor(m, 8));
    float e = __expf(v - m);
    float sum = e;
    sum += __shfl_xor(sum, 1);
    sum += __shfl_xor(sum, 2);
    sum += __shfl_xor(sum, 4);
    sum += __shfl_xor(sum, 8);
    float p = e / sum;
    Pb[(quad * 4 + r) * 40 + lidx] = f2bf_bits(p);
  }
  __syncthreads();

  f32x4 o[4];
  #pragma unroll
  for (int n4 = 0; n4 < 4; n4++){
    bf16x8 a = *(const bf16x8*)(Pb + lidx * 40 + quad * 8);
    bf16x8 b = *(const bf16x8*)(Vt + (n4 * 16 + lidx) * 40 + quad * 8);
    o[n4] = __builtin_amdgcn_mfma_f32_16x16x32_bf16(a, b, (f32x4){0.f,0.f,0.f,0.f}, 0, 0, 0);
  }

  #pragma unroll
  for (int n4 = 0; n4 < 4; n4++)
    #pragma unroll
    for (int r = 0; r < 4; r++)
      Qb[(quad * 4 + r) * 72 + n4 * 16 + lidx] = f2bf_bits(o[n4][r]);
  __syncthreads();

  unsigned short* dst = aout + (size_t)pos * 1024;
  #pragma unroll
  for (int t = 0; t < 2; t++){
    int j = lane * 2 + t;
    int h = j >> 3, dc = j & 7;
    uint4 u = *(const uint4*)(Qb + h * 72 + dc * 8);
    *(uint4*)(dst + j * 8) = u;
  }
}

// ---------- in-place LayerNorm over rows of 1024 fp32 ----------
__global__ __launch_bounds__(256) void k_ln(float* __restrict__ out,
                                            const float* __restrict__ gamma,
                                            const float* __restrict__ beta){
  __shared__ float red[8];
  int tid = threadIdx.x;
  float4* rowp = (float4*)(out + (size_t)blockIdx.x * 1024);
  float4 v = rowp[tid];
  float s  = v.x + v.y + v.z + v.w;
  float ss = v.x * v.x + v.y * v.y + v.z * v.z + v.w * v.w;
  #pragma unroll
  for (int off = 32; off > 0; off >>= 1){
    s  += __shfl_down(s, off);
    ss += __shfl_down(ss, off);
  }
  if ((tid & 63) == 0){ red[tid >> 6] = s; red[4 + (tid >> 6)] = ss; }
  __syncthreads();
  float S  = red[0] + red[1] + red[2] + red[3];
  float SS = red[4] + red[5] + red[6] + red[7];
  float mean = S * (1.0f / 1024.0f);
  float var  = SS * (1.0f / 1024.0f) - mean * mean;
  float rstd = rsqrtf(var + 1e-5f);
  float4 g = ((const float4*)gamma)[tid];
  float4 b = ((const float4*)beta)[tid];
  v.x = (v.x - mean) * rstd * g.x + b.x;
  v.y = (v.y - mean) * rstd * g.y + b.y;
  v.z = (v.z - mean) * rstd * g.z + b.z;
  v.w = (v.w - mean) * rstd * g.w + b.w;
  rowp[tid] = v;
}

extern "C" void kernel_launch(void* const* d_in, const int* in_sizes, int n_in,
                              void* d_out, int out_size, void* d_ws, size_t ws_size,
                              hipStream_t stream){
  const float* x     = (const float*)d_in[0];
  const float* Wq    = (const float*)d_in[1];
  const float* bq    = (const float*)d_in[2];
  const float* Wk    = (const float*)d_in[3];
  const float* bk    = (const float*)d_in[4];
  const float* Wv    = (const float*)d_in[5];
  const float* bv    = (const float*)d_in[6];
  const float* Wo    = (const float*)d_in[7];
  const float* bo    = (const float*)d_in[8];
  const float* gamma = (const float*)d_in[9];
  const float* beta  = (const float*)d_in[10];
  float* out = (float*)d_out;

  // workspace layout (bytes):
  //   [0, 6291456)            Wqkv^T bf16 (3072 x 1024)
  //   [6291456, 8388608)      Wo^T bf16  (1024 x 1024)
  //   [8388608, 75497472)     xb bf16 (32768 x 1024); reused as attn-out after GEMM1
  //   [75497472, 276824064)   qkv bf16 (32768 x 3072)
  char* ws = (char*)d_ws;
  unsigned short* Wqkv_t = (unsigned short*)ws;
  unsigned short* Wo_t   = (unsigned short*)(ws + 6291456);
  unsigned short* xb     = (unsigned short*)(ws + 8388608);
  unsigned short* qkv    = (unsigned short*)(ws + 75497472);
  unsigned short* aout   = xb;   // reuse: xb consumed by GEMM1 before attention writes

  // 1) x -> bf16
  k_convert_bf16<<<32768, 256, 0, stream>>>(x, xb, (MM * FFD) / 4);

  // 2) weight transposes (fp32 KxN -> bf16 NxK)
  dim3 tb(32, 8), tg(32, 32);
  k_transpose_bf16<<<tg, tb, 0, stream>>>(Wq, Wqkv_t,                1024, 1024);
  k_transpose_bf16<<<tg, tb, 0, stream>>>(Wk, Wqkv_t + 1024 * 1024,  1024, 1024);
  k_transpose_bf16<<<tg, tb, 0, stream>>>(Wv, Wqkv_t + 2048 * 1024,  1024, 1024);
  k_transpose_bf16<<<tg, tb, 0, stream>>>(Wo, Wo_t,                  1024, 1024);

  // 3) QKV GEMM: (32768 x 1024) @ (1024 x 3072) -> bf16  (grid 12x128 = 1536 blocks)
  k_gemm_bt<true><<<dim3(NQKV / 256, MM / 256), 512, 0, stream>>>(
      xb, Wqkv_t, bq, bk, bv, qkv, MM, NQKV, FFD);

  // 4) per-position head attention (MFMA)
  k_attention<<<MM / 4, 256, 0, stream>>>(qkv, aout);

  // 5) output GEMM: (32768 x 1024) @ (1024 x 1024) + bo -> fp32 d_out (grid 4x128 = 512)
  k_gemm_bt<false><<<dim3(FFD / 256, MM / 256), 512, 0, stream>>>(
      aout, Wo_t, bo, bo, bo, out, MM, FFD, FFD);

  // 6) LayerNorm in-place
  k_ln<<<MM, 256, 0, stream>>>(out, gamma, beta);
}

// Round 2
// 631.047 us; speedup vs baseline: 1.1188x; 1.0384x over previous
//
#include <hip/hip_runtime.h>
#include <hip/hip_bf16.h>
#include <stdint.h>

// Problem constants
#define MM   32768   // B*S
#define FFD  1024    // F
#define NQKV 3072    // 3*F

typedef __bf16 bf16x8 __attribute__((ext_vector_type(8)));
typedef float  f32x4  __attribute__((ext_vector_type(4)));

__device__ __forceinline__ unsigned short f2bf_bits(float f){
  __hip_bfloat16 h = __float2bfloat16(f);
  unsigned short u;
  __builtin_memcpy(&u, &h, 2);
  return u;
}

__device__ __forceinline__ void gld16(const void* g, void* l){
  const unsigned int* gu = (const unsigned int*)g;
  unsigned int* lu = (unsigned int*)l;
  __builtin_amdgcn_global_load_lds(
      (const __attribute__((address_space(1))) unsigned int*)gu,
      (__attribute__((address_space(3))) unsigned int*)lu,
      16, 0, 0);
}

// Raw barrier (no vmcnt(0) auto-drain like __syncthreads) + compiler memory fence
#define BARRIER() do { asm volatile("" ::: "memory"); \
                       __builtin_amdgcn_s_barrier();  \
                       asm volatile("" ::: "memory"); } while(0)

// ---------- convert fp32 -> bf16, 4 elems/thread ----------
__global__ __launch_bounds__(256) void k_convert_bf16(const float* __restrict__ in,
                                                      unsigned short* __restrict__ out,
                                                      int n4){
  int i = blockIdx.x * 256 + threadIdx.x;
  if (i >= n4) return;
  float4 v = ((const float4*)in)[i];
  ushort4 r;
  r.x = f2bf_bits(v.x); r.y = f2bf_bits(v.y);
  r.z = f2bf_bits(v.z); r.w = f2bf_bits(v.w);
  ((ushort4*)out)[i] = r;
}

// ---------- transpose-convert: out(N x K bf16) = in(K x N fp32)^T ----------
__global__ __launch_bounds__(256) void k_transpose_bf16(const float* __restrict__ in,
                                                        unsigned short* __restrict__ out,
                                                        int rows, int cols){
  __shared__ float tile[32][33];
  int bc = blockIdx.x * 32, br = blockIdx.y * 32;
  int tx = threadIdx.x, ty = threadIdx.y;
  #pragma unroll
  for (int j = 0; j < 32; j += 8)
    tile[ty + j][tx] = in[(size_t)(br + ty + j) * cols + bc + tx];
  __syncthreads();
  #pragma unroll
  for (int j = 0; j < 32; j += 8)
    out[(size_t)(bc + ty + j) * rows + br + tx] = f2bf_bits(tile[tx][ty + j]);
}

// ---------- bf16 MFMA GEMM: C(MxN) = A(MxK) * Bt(NxK)^T + bias ----------
// 256x256 tile, BK=32, 512 threads (8 waves, 2Mx4N), 16x16x32 MFMA.
// Ring-4 LDS (4 x 32KB), staged 3 K-tiles ahead via global_load_lds.
// ONE {counted s_waitcnt vmcnt; s_barrier} per K-tile — the ring makes
// intra-tile barriers unnecessary (buffer immutable during the tile; the
// staging slot was last read a full tile ago, certified by the barrier).
// The 12 ds_read_b128 + 32 MFMA + 4 global_load_lds tile body is left to the
// compiler to software-schedule (reads overlap MFMA; waves drift freely).
// XOR bank swizzle byte^=((row>>1)&3)<<4 on reads, pre-inverted on the
// per-lane GLOBAL source (LDS dest stays linear per global_load_lds rules).
template <bool BF16OUT>
__global__ __launch_bounds__(512, 2) void k_gemm_bt(
    const unsigned short* __restrict__ A,
    const unsigned short* __restrict__ Bt,
    const float* __restrict__ b0, const float* __restrict__ b1, const float* __restrict__ b2,
    void* __restrict__ Cout, int M, int N, int K)
{
  __shared__ alignas(16) char smem[131072];

  const int tid  = threadIdx.x;
  const int lane = tid & 63;
  const int wave = tid >> 6;
  const int wr = wave >> 2, wc = wave & 3;       // 2 x 4 wave grid
  const int quad = lane >> 4, lrow = lane & 15;
  const int sa = ((lrow >> 1) & 3) << 4;         // read-side XOR swizzle bits

  // XCD-aware bijective block swizzle (both launch grids are multiples of 8)
  const int nwgx = gridDim.x;
  int nwg = nwgx * gridDim.y;
  int bid = blockIdx.y * nwgx + blockIdx.x;
  int cpx = nwg >> 3;
  int nid = (bid & 7) * cpx + (bid >> 3);
  int by = nid / nwgx;
  int bx = nid - by * nwgx;

  const long rowBase = (long)by * 256;
  const long colBase = (long)bx * 256;

  f32x4 acc[8][4];
  #pragma unroll
  for (int i = 0; i < 8; i++)
    #pragma unroll
    for (int j = 0; j < 4; j++)
      acc[i][j] = (f32x4){0.f, 0.f, 0.f, 0.f};

  // staging: thread t covers row (t>>2) of a 128-row half, 16B chunk (t&3),
  // with the global column pre-swizzled so linear LDS + swizzled reads match.
  const int swz8 = 8 * ((tid & 3) ^ ((tid >> 3) & 3));
  const unsigned short* gA = A  + (rowBase + (tid >> 2)) * (long)K + swz8;
  const unsigned short* gB = Bt + (colBase + (tid >> 2)) * (long)K + swz8;
  const long hstep = 128L * K;   // 128 rows, in elements

  const int nk = K >> 5;         // number of 32-wide K tiles (K=1024 -> 32)

  // prologue: stage tiles 0..2 into ring slots 0..2 (12 loads/thread)
  #pragma unroll
  for (int tt = 0; tt < 3; ++tt){
    char* nb = smem + tt * 32768;
    gld16(gA + tt * 32,         nb +         tid * 16);
    gld16(gA + tt * 32 + hstep, nb +  8192 + tid * 16);
    gld16(gB + tt * 32,         nb + 16384 + tid * 16);
    gld16(gB + tt * 32 + hstep, nb + 24576 + tid * 16);
  }

  for (int t = 0; t < nk; ++t){
    // counted wait: certify this tile's 4 loads landed; keep up to 8 in flight
    if (t <= nk - 3)      asm volatile("s_waitcnt vmcnt(8)" ::: "memory");
    else if (t == nk - 2) asm volatile("s_waitcnt vmcnt(4)" ::: "memory");
    else                  asm volatile("s_waitcnt vmcnt(0)" ::: "memory");
    BARRIER();   // all waves' loads for tile t landed; slot (t+3)&3 free

    char* buf = smem + (t & 3) * 32768;
    if (t < nk - 3){
      char* nb = smem + ((t + 3) & 3) * 32768;
      const unsigned short* sA = gA + (long)(t + 3) * 32;
      const unsigned short* sB = gB + (long)(t + 3) * 32;
      gld16(sA,         nb +         tid * 16);
      gld16(sA + hstep, nb +  8192 + tid * 16);
      gld16(sB,         nb + 16384 + tid * 16);
      gld16(sB + 24576 / 16 * 0 + hstep, nb + 24576 + tid * 16);
    }

    // tile body: 4 B frags (reused across both M-halves) + 2x{4 A frags, 16 MFMA}
    bf16x8 bfr[4];
    const char* bb = buf + 16384 + wc * 4096 + lrow * 64 + ((quad * 16) ^ sa);
    #pragma unroll
    for (int n = 0; n < 4; ++n)
      bfr[n] = *(const bf16x8*)(bb + n * 1024);

    #pragma unroll
    for (int p = 0; p < 2; ++p){
      bf16x8 af[4];
      const char* ab = buf + wr * 8192 + p * 4096 + lrow * 64 + ((quad * 16) ^ sa);
      #pragma unroll
      for (int f = 0; f < 4; ++f)
        af[f] = *(const bf16x8*)(ab + f * 1024);
      __builtin_amdgcn_s_setprio(1);
      #pragma unroll
      for (int f = 0; f < 4; ++f)
        #pragma unroll
        for (int n = 0; n < 4; ++n)
          acc[p * 4 + f][n] =
              __builtin_amdgcn_mfma_f32_16x16x32_bf16(af[f], bfr[n], acc[p * 4 + f][n], 0, 0, 0);
      __builtin_amdgcn_s_setprio(0);
    }
  }

  // ---------------- epilogue ----------------
  // C/D layout: col = lane&15, row-in-frag = quad*4 + r
  if constexpr (BF16OUT){
    // LDS-bounce epilogue: scatter acc -> swizzled LDS, then fully-coalesced
    // 16B global stores (kills the 1.6x partial-line write amplification).
    BARRIER();   // all waves done reading K-loop LDS
    #pragma unroll
    for (int n = 0; n < 4; ++n){
      int lcol = wc * 64 + n * 16 + lrow;
      long col = colBase + lcol;
      const float* bp = (col < 1024) ? b0 : ((col < 2048) ? b1 : b2);
      float bias = bp[col & 1023];
      #pragma unroll
      for (int m = 0; m < 8; ++m){
        int row0 = wr * 128 + (m >> 2) * 64 + (m & 3) * 16 + quad * 4;
        int sw = ((row0 >> 2) & 3) << 5;          // same for r=0..3
        #pragma unroll
        for (int r = 0; r < 4; ++r){
          float v = acc[m][n][r] + bias;
          int byte = (row0 + r) * 512 + ((lcol * 2) ^ sw);
          *(unsigned short*)(smem + byte) = f2bf_bits(v);
        }
      }
    }
    asm volatile("s_waitcnt lgkmcnt(0)" ::: "memory");
    BARRIER();
    // copy out: 8192 16B chunks; thread t takes chunks t + 512*i
    unsigned short* Cо = (unsigned short*)Cout;
    #pragma unroll
    for (int i = 0; i < 16; ++i){
      int c = i * 512 + tid;
      int row = c >> 5, cidx = c & 31;
      int rb = (cidx ^ (((row >> 2) & 3) << 1)) * 16;
      uint4 u = *(const uint4*)(smem + row * 512 + rb);
      *(uint4*)(Cо + (rowBase + row) * (long)N + colBase + cidx * 8) = u;
    }
  } else {
    #pragma unroll
    for (int n = 0; n < 4; ++n){
      long col = colBase + wc * 64 + n * 16 + lrow;
      const float* bp = (col < 1024) ? b0 : ((col < 2048) ? b1 : b2);
      float bias = bp[col & 1023];
      #pragma unroll
      for (int m = 0; m < 8; ++m){
        long row0 = rowBase + wr * 128 + (m >> 2) * 64 + (m & 3) * 16 + quad * 4;
        #pragma unroll
        for (int r = 0; r < 4; ++r){
          float v = acc[m][n][r] + bias;
          ((float*)Cout)[(row0 + r) * (long)N + col] = v;
        }
      }
    }
  }
}

// ---------- per-position head-attention via MFMA ----------
__global__ __launch_bounds__(256) void k_attention(const unsigned short* __restrict__ qkv,
                                                   unsigned short* __restrict__ aout){
  constexpr int QOFF = 0;            // [16][72] = 1152
  constexpr int KOFF = 1152;         // [16][72] = 1152
  constexpr int VOFF = 2304;         // [64][40] = 2560
  constexpr int POFF = 4864;         // [16][40] = 640
  constexpr int PER  = 5504;         // ushorts per wave
  __shared__ unsigned short smem[4 * PER];

  const int lane = threadIdx.x & 63;
  const int wave = threadIdx.x >> 6;
  const int pos  = blockIdx.x * 4 + wave;
  const int quad = lane >> 4, lidx = lane & 15;

  unsigned short* base = smem + wave * PER;
  unsigned short* Qb = base + QOFF;
  unsigned short* Kb = base + KOFF;
  unsigned short* Vt = base + VOFF;
  unsigned short* Pb = base + POFF;

  {
    uint4 z = {0u, 0u, 0u, 0u};
    *(uint4*)(Vt + lane * 40 + 16) = z;
    *(uint4*)(Vt + lane * 40 + 24) = z;
    *(uint2*)(Pb + (lane >> 2) * 40 + 16 + (lane & 3) * 4) = make_uint2(0u, 0u);
  }

  const unsigned short* src = qkv + (size_t)pos * 3072;
  #pragma unroll
  for (int i = 0; i < 6; i++){
    int c = i * 64 + lane;
    uint4 u = *(const uint4*)(src + c * 8);
    if (i < 4){
      unsigned short* mb = (c < 128) ? Qb : Kb;
      int cc = c & 127;
      *(uint4*)(mb + (cc >> 3) * 72 + (cc & 7) * 8) = u;
    } else {
      int cv = c - 256;
      int g = cv >> 3, d0 = (cv & 7) * 8;
      const unsigned short* us = (const unsigned short*)&u;
      #pragma unroll
      for (int t = 0; t < 8; t++) Vt[(d0 + t) * 40 + g] = us[t];
    }
  }
  __syncthreads();

  f32x4 s = (f32x4){0.f, 0.f, 0.f, 0.f};
  #pragma unroll
  for (int kk = 0; kk < 2; kk++){
    bf16x8 a = *(const bf16x8*)(Qb + lidx * 72 + kk * 32 + quad * 8);
    bf16x8 b = *(const bf16x8*)(Kb + lidx * 72 + kk * 32 + quad * 8);
    s = __builtin_amdgcn_mfma_f32_16x16x32_bf16(a, b, s, 0, 0, 0);
  }

  #pragma unroll
  for (int r = 0; r < 4; r++){
    float v = s[r] * 0.125f;
    float m = v;
    m = fmaxf(m, __shfl_xor(m, 1));
    m = fmaxf(m, __shfl_xor(m, 2));
    m = fmaxf(m, __shfl_xor(m, 4));
    m = fmaxf(m, __shfl_xor(m, 8));
    float e = __expf(v - m);
    float sum = e;
    sum += __shfl_xor(sum, 1);
    sum += __shfl_xor(sum, 2);
    sum += __shfl_xor(sum, 4);
    sum += __shfl_xor(sum, 8);
    float p = e / sum;
    Pb[(quad * 4 + r) * 40 + lidx] = f2bf_bits(p);
  }
  __syncthreads();

  f32x4 o[4];
  #pragma unroll
  for (int n4 = 0; n4 < 4; n4++){
    bf16x8 a = *(const bf16x8*)(Pb + lidx * 40 + quad * 8);
    bf16x8 b = *(const bf16x8*)(Vt + (n4 * 16 + lidx) * 40 + quad * 8);
    o[n4] = __builtin_amdgcn_mfma_f32_16x16x32_bf16(a, b, (f32x4){0.f,0.f,0.f,0.f}, 0, 0, 0);
  }

  #pragma unroll
  for (int n4 = 0; n4 < 4; n4++)
    #pragma unroll
    for (int r = 0; r < 4; r++)
      Qb[(quad * 4 + r) * 72 + n4 * 16 + lidx] = f2bf_bits(o[n4][r]);
  __syncthreads();

  unsigned short* dst = aout + (size_t)pos * 1024;
  #pragma unroll
  for (int t = 0; t < 2; t++){
    int j = lane * 2 + t;
    int h = j >> 3, dc = j & 7;
    uint4 u = *(const uint4*)(Qb + h * 72 + dc * 8);
    *(uint4*)(dst + j * 8) = u;
  }
}

// ---------- in-place LayerNorm over rows of 1024 fp32 ----------
__global__ __launch_bounds__(256) void k_ln(float* __restrict__ out,
                                            const float* __restrict__ gamma,
                                            const float* __restrict__ beta){
  __shared__ float red[8];
  int tid = threadIdx.x;
  float4* rowp = (float4*)(out + (size_t)blockIdx.x * 1024);
  float4 v = rowp[tid];
  float s  = v.x + v.y + v.z + v.w;
  float ss = v.x * v.x + v.y * v.y + v.z * v.z + v.w * v.w;
  #pragma unroll
  for (int off = 32; off > 0; off >>= 1){
    s  += __shfl_down(s, off);
    ss += __shfl_down(ss, off);
  }
  if ((tid & 63) == 0){ red[tid >> 6] = s; red[4 + (tid >> 6)] = ss; }
  __syncthreads();
  float S  = red[0] + red[1] + red[2] + red[3];
  float SS = red[4] + red[5] + red[6] + red[7];
  float mean = S * (1.0f / 1024.0f);
  float var  = SS * (1.0f / 1024.0f) - mean * mean;
  float rstd = rsqrtf(var + 1e-5f);
  float4 g = ((const float4*)gamma)[tid];
  float4 b = ((const float4*)beta)[tid];
  v.x = (v.x - mean) * rstd * g.x + b.x;
  v.y = (v.y - mean) * rstd * g.y + b.y;
  v.z = (v.z - mean) * rstd * g.z + b.z;
  v.w = (v.w - mean) * rstd * g.w + b.w;
  rowp[tid] = v;
}

extern "C" void kernel_launch(void* const* d_in, const int* in_sizes, int n_in,
                              void* d_out, int out_size, void* d_ws, size_t ws_size,
                              hipStream_t stream){
  const float* x     = (const float*)d_in[0];
  const float* Wq    = (const float*)d_in[1];
  const float* bq    = (const float*)d_in[2];
  const float* Wk    = (const float*)d_in[3];
  const float* bk    = (const float*)d_in[4];
  const float* Wv    = (const float*)d_in[5];
  const float* bv    = (const float*)d_in[6];
  const float* Wo    = (const float*)d_in[7];
  const float* bo    = (const float*)d_in[8];
  const float* gamma = (const float*)d_in[9];
  const float* beta  = (const float*)d_in[10];
  float* out = (float*)d_out;

  // workspace layout (bytes):
  //   [0, 6291456)            Wqkv^T bf16 (3072 x 1024)
  //   [6291456, 8388608)      Wo^T bf16  (1024 x 1024)
  //   [8388608, 75497472)     xb bf16 (32768 x 1024); reused as attn-out after GEMM1
  //   [75497472, 276824064)   qkv bf16 (32768 x 3072)
  char* ws = (char*)d_ws;
  unsigned short* Wqkv_t = (unsigned short*)ws;
  unsigned short* Wo_t   = (unsigned short*)(ws + 6291456);
  unsigned short* xb     = (unsigned short*)(ws + 8388608);
  unsigned short* qkv    = (unsigned short*)(ws + 75497472);
  unsigned short* aout   = xb;   // reuse: xb consumed by GEMM1 before attention writes

  // 1) x -> bf16
  k_convert_bf16<<<32768, 256, 0, stream>>>(x, xb, (MM * FFD) / 4);

  // 2) weight transposes (fp32 KxN -> bf16 NxK)
  dim3 tb(32, 8), tg(32, 32);
  k_transpose_bf16<<<tg, tb, 0, stream>>>(Wq, Wqkv_t,                1024, 1024);
  k_transpose_bf16<<<tg, tb, 0, stream>>>(Wk, Wqkv_t + 1024 * 1024,  1024, 1024);
  k_transpose_bf16<<<tg, tb, 0, stream>>>(Wv, Wqkv_t + 2048 * 1024,  1024, 1024);
  k_transpose_bf16<<<tg, tb, 0, stream>>>(Wo, Wo_t,                  1024, 1024);

  // 3) QKV GEMM: (32768 x 1024) @ (1024 x 3072) -> bf16  (grid 12x128 = 1536 blocks)
  k_gemm_bt<true><<<dim3(NQKV / 256, MM / 256), 512, 0, stream>>>(
      xb, Wqkv_t, bq, bk, bv, qkv, MM, NQKV, FFD);

  // 4) per-position head attention (MFMA)
  k_attention<<<MM / 4, 256, 0, stream>>>(qkv, aout);

  // 5) output GEMM: (32768 x 1024) @ (1024 x 1024) + bo -> fp32 d_out (grid 4x128 = 512)
  k_gemm_bt<false><<<dim3(FFD / 256, MM / 256), 512, 0, stream>>>(
      aout, Wo_t, bo, bo, bo, out, MM, FFD, FFD);

  // 6) LayerNorm in-place
  k_ln<<<MM, 256, 0, stream>>>(out, gamma, beta);
}

// Round 4
// 626.791 us; speedup vs baseline: 1.1264x; 1.0068x over previous
//
#include <hip/hip_runtime.h>
#include <hip/hip_bf16.h>
#include <stdint.h>

// Problem constants
#define MM   32768   // B*S
#define FFD  1024    // F
#define NQKV 3072    // 3*F

typedef __bf16 bf16x8 __attribute__((ext_vector_type(8)));
typedef float  f32x4  __attribute__((ext_vector_type(4)));

__device__ __forceinline__ unsigned short f2bf_bits(float f){
  __hip_bfloat16 h = __float2bfloat16(f);
  unsigned short u;
  __builtin_memcpy(&u, &h, 2);
  return u;
}

__device__ __forceinline__ void gld16(const void* g, void* l){
  const unsigned int* gu = (const unsigned int*)g;
  unsigned int* lu = (unsigned int*)l;
  __builtin_amdgcn_global_load_lds(
      (const __attribute__((address_space(1))) unsigned int*)gu,
      (__attribute__((address_space(3))) unsigned int*)lu,
      16, 0, 0);
}

// Raw barrier (no vmcnt(0) auto-drain like __syncthreads) + compiler memory fence
#define BARRIER() do { asm volatile("" ::: "memory"); \
                       __builtin_amdgcn_s_barrier();  \
                       asm volatile("" ::: "memory"); } while(0)

// ---------- convert fp32 -> bf16, 4 elems/thread ----------
__global__ __launch_bounds__(256) void k_convert_bf16(const float* __restrict__ in,
                                                      unsigned short* __restrict__ out,
                                                      int n4){
  int i = blockIdx.x * 256 + threadIdx.x;
  if (i >= n4) return;
  float4 v = ((const float4*)in)[i];
  ushort4 r;
  r.x = f2bf_bits(v.x); r.y = f2bf_bits(v.y);
  r.z = f2bf_bits(v.z); r.w = f2bf_bits(v.w);
  ((ushort4*)out)[i] = r;
}

// ---------- transpose-convert: out(N x K bf16) = in(K x N fp32)^T ----------
__global__ __launch_bounds__(256) void k_transpose_bf16(const float* __restrict__ in,
                                                        unsigned short* __restrict__ out,
                                                        int rows, int cols){
  __shared__ float tile[32][33];
  int bc = blockIdx.x * 32, br = blockIdx.y * 32;
  int tx = threadIdx.x, ty = threadIdx.y;
  #pragma unroll
  for (int j = 0; j < 32; j += 8)
    tile[ty + j][tx] = in[(size_t)(br + ty + j) * cols + bc + tx];
  __syncthreads();
  #pragma unroll
  for (int j = 0; j < 32; j += 8)
    out[(size_t)(bc + ty + j) * rows + br + tx] = f2bf_bits(tile[tx][ty + j]);
}

// ---------- bf16 MFMA GEMM: C(MxN) = A(MxK) * Bt(NxK)^T + bias ----------
// 256x256 tile, BK=32, 512 threads (8 waves, 2Mx4N), 16x16x32 MFMA.
// Ring-4 LDS (4 x 32KB), staged 3 K-tiles ahead via global_load_lds.
// WHOLE-TILE certification: one counted {s_waitcnt vmcnt(8); s_barrier} per
// K-tile (never 0 mid-loop) -- this is what round-3's half-tile counting got
// wrong (waves read M/N-halves every phase, so only full-tile certify works).
// On top: m201-style intra-tile phase interleave -- per tile 2 phases of
//   {ds_read frags | 2 global_load_lds of tile t+3 | barrier |
//    lgkmcnt(0)+sched_barrier | setprio(1) 16 MFMA setprio(0) | barrier}
// which creates the wave role-split that makes counted-vmcnt and setprio pay.
// XOR chunk swizzle slot=chunk^((row>>1)&3) on reads, pre-inverted on the
// per-lane GLOBAL source (gld16 LDS dest stays linear).
template <bool BF16OUT>
__global__ __launch_bounds__(512, 2) void k_gemm_bt(
    const unsigned short* __restrict__ A,
    const unsigned short* __restrict__ Bt,
    const float* __restrict__ b0, const float* __restrict__ b1, const float* __restrict__ b2,
    void* __restrict__ Cout, int M, int N, int K)
{
  __shared__ alignas(16) char smem[131072];

  const int tid  = threadIdx.x;
  const int lane = tid & 63;
  const int wave = tid >> 6;
  const int wr = wave >> 2, wc = wave & 3;       // 2 x 4 wave grid
  const int quad = lane >> 4, lrow = lane & 15;
  const int sa = ((lrow >> 1) & 3) << 4;         // read-side XOR swizzle bits

  // XCD-aware bijective block swizzle (both launch grids are multiples of 8)
  const int nwgx = gridDim.x;
  int nwg = nwgx * gridDim.y;
  int bid = blockIdx.y * nwgx + blockIdx.x;
  int cpx = nwg >> 3;
  int nid = (bid & 7) * cpx + (bid >> 3);
  int by = nid / nwgx;
  int bx = nid - by * nwgx;

  const long rowBase = (long)by * 256;
  const long colBase = (long)bx * 256;

  f32x4 acc[8][4];
  #pragma unroll
  for (int i = 0; i < 8; i++)
    #pragma unroll
    for (int j = 0; j < 4; j++)
      acc[i][j] = (f32x4){0.f, 0.f, 0.f, 0.f};

  // staging: thread t covers row (t>>2) of a 128-row half, 16B chunk (t&3),
  // with the global chunk pre-swizzled so linear LDS + swizzled reads match.
  const int swz8 = 8 * ((tid & 3) ^ ((tid >> 3) & 3));
  const unsigned short* gA = A  + (rowBase + (tid >> 2)) * (long)K + swz8;
  const unsigned short* gB = Bt + (colBase + (tid >> 2)) * (long)K + swz8;
  const long hstep = 128L * K;   // 128 rows, in elements

  const int nk = K >> 5;         // number of 32-wide K tiles (K=1024 -> 32)

  // prologue: stage tiles 0..2 into ring slots 0..2 (12 loads/thread)
  #pragma unroll
  for (int tt = 0; tt < 3; ++tt){
    char* nb = smem + tt * 32768;
    gld16(gA + tt * 32,         nb +         tid * 16);
    gld16(gA + tt * 32 + hstep, nb +  8192 + tid * 16);
    gld16(gB + tt * 32,         nb + 16384 + tid * 16);
    gld16(gB + tt * 32 + hstep, nb + 24576 + tid * 16);
  }

  for (int t = 0; t < nk; ++t){
    // counted wait: certify ALL of tile t's 12 halves... i.e. its 4 loads
    // (8 newer loads for t+1,t+2 stay in flight); never 0 mid-loop.
    if (t <= nk - 3)      asm volatile("s_waitcnt vmcnt(8)" ::: "memory");
    else if (t == nk - 2) asm volatile("s_waitcnt vmcnt(4)" ::: "memory");
    else                  asm volatile("s_waitcnt vmcnt(0)" ::: "memory");
    BARRIER();   // all waves' loads for tile t landed; slot (t+3)&3 free

    char* buf = smem + (t & 3) * 32768;
    char* nb  = smem + ((t + 3) & 3) * 32768;
    const bool st = (t < nk - 3);
    const unsigned short* sA = gA + (long)(t + 3) * 32;
    const unsigned short* sB = gB + (long)(t + 3) * 32;

    // ---- phase 0: read B frags (tile-wide) + A(mh0); stage A halves of t+3
    bf16x8 bfr[4], af[4];
    const char* bb = buf + 16384 + wc * 4096 + lrow * 64 + ((quad * 16) ^ sa);
    #pragma unroll
    for (int n = 0; n < 4; ++n)
      bfr[n] = *(const bf16x8*)(bb + n * 1024);
    const char* ab0 = buf + wr * 8192 + lrow * 64 + ((quad * 16) ^ sa);
    #pragma unroll
    for (int f = 0; f < 4; ++f)
      af[f] = *(const bf16x8*)(ab0 + f * 1024);
    if (st){
      gld16(sA,         nb +        tid * 16);
      gld16(sA + hstep, nb + 8192 + tid * 16);
    }
    BARRIER();
    asm volatile("s_waitcnt lgkmcnt(0)" ::: "memory");
    __builtin_amdgcn_sched_barrier(0);
    __builtin_amdgcn_s_setprio(1);
    #pragma unroll
    for (int f = 0; f < 4; ++f)
      #pragma unroll
      for (int n = 0; n < 4; ++n)
        acc[f][n] = __builtin_amdgcn_mfma_f32_16x16x32_bf16(af[f], bfr[n], acc[f][n], 0, 0, 0);
    __builtin_amdgcn_s_setprio(0);
    BARRIER();

    // ---- phase 1: read A(mh1); stage B halves of t+3
    const char* ab1 = buf + wr * 8192 + 4096 + lrow * 64 + ((quad * 16) ^ sa);
    #pragma unroll
    for (int f = 0; f < 4; ++f)
      af[f] = *(const bf16x8*)(ab1 + f * 1024);
    if (st){
      gld16(sB,         nb + 16384 + tid * 16);
      gld16(sB + hstep, nb + 24576 + tid * 16);
    }
    BARRIER();
    asm volatile("s_waitcnt lgkmcnt(0)" ::: "memory");
    __builtin_amdgcn_sched_barrier(0);
    __builtin_amdgcn_s_setprio(1);
    #pragma unroll
    for (int f = 0; f < 4; ++f)
      #pragma unroll
      for (int n = 0; n < 4; ++n)
        acc[4 + f][n] = __builtin_amdgcn_mfma_f32_16x16x32_bf16(af[f], bfr[n], acc[4 + f][n], 0, 0, 0);
    __builtin_amdgcn_s_setprio(0);
    // loop-back performs the counted vmcnt + tile-boundary barrier
  }

  // ---------------- epilogue ----------------
  // C/D layout: col = lane&15, row-in-frag = quad*4 + r
  if constexpr (BF16OUT){
    // LDS-bounce epilogue: scatter acc -> swizzled LDS, then fully-coalesced
    // 16B global stores (kills partial-line write amplification).
    BARRIER();   // all waves done reading K-loop LDS
    #pragma unroll
    for (int n = 0; n < 4; ++n){
      int lcol = wc * 64 + n * 16 + lrow;
      long col = colBase + lcol;
      const float* bp = (col < 1024) ? b0 : ((col < 2048) ? b1 : b2);
      float bias = bp[col & 1023];
      #pragma unroll
      for (int m = 0; m < 8; ++m){
        int row0 = wr * 128 + (m >> 2) * 64 + (m & 3) * 16 + quad * 4;
        int sw = ((row0 >> 2) & 3) << 5;          // same for r=0..3
        #pragma unroll
        for (int r = 0; r < 4; ++r){
          float v = acc[m][n][r] + bias;
          int byte = (row0 + r) * 512 + ((lcol * 2) ^ sw);
          *(unsigned short*)(smem + byte) = f2bf_bits(v);
        }
      }
    }
    asm volatile("s_waitcnt lgkmcnt(0)" ::: "memory");
    BARRIER();
    // copy out: 8192 16B chunks; thread t takes chunks t + 512*i
    unsigned short* Cb = (unsigned short*)Cout;
    #pragma unroll
    for (int i = 0; i < 16; ++i){
      int c = i * 512 + tid;
      int row = c >> 5, cidx = c & 31;
      int rb = (cidx ^ (((row >> 2) & 3) << 1)) * 16;
      uint4 u = *(const uint4*)(smem + row * 512 + rb);
      *(uint4*)(Cb + (rowBase + row) * (long)N + colBase + cidx * 8) = u;
    }
  } else {
    #pragma unroll
    for (int n = 0; n < 4; ++n){
      long col = colBase + wc * 64 + n * 16 + lrow;
      const float* bp = (col < 1024) ? b0 : ((col < 2048) ? b1 : b2);
      float bias = bp[col & 1023];
      #pragma unroll
      for (int m = 0; m < 8; ++m){
        long row0 = rowBase + wr * 128 + (m >> 2) * 64 + (m & 3) * 16 + quad * 4;
        #pragma unroll
        for (int r = 0; r < 4; ++r){
          float v = acc[m][n][r] + bias;
          ((float*)Cout)[(row0 + r) * (long)N + col] = v;
        }
      }
    }
  }
}

// ---------- per-position head-attention via MFMA ----------
__global__ __launch_bounds__(256) void k_attention(const unsigned short* __restrict__ qkv,
                                                   unsigned short* __restrict__ aout){
  constexpr int QOFF = 0;            // [16][72] = 1152
  constexpr int KOFF = 1152;         // [16][72] = 1152
  constexpr int VOFF = 2304;         // [64][40] = 2560
  constexpr int POFF = 4864;         // [16][40] = 640
  constexpr int PER  = 5504;         // ushorts per wave
  __shared__ unsigned short smem[4 * PER];

  const int lane = threadIdx.x & 63;
  const int wave = threadIdx.x >> 6;
  const int pos  = blockIdx.x * 4 + wave;
  const int quad = lane >> 4, lidx = lane & 15;

  unsigned short* base = smem + wave * PER;
  unsigned short* Qb = base + QOFF;
  unsigned short* Kb = base + KOFF;
  unsigned short* Vt = base + VOFF;
  unsigned short* Pb = base + POFF;

  {
    uint4 z = {0u, 0u, 0u, 0u};
    *(uint4*)(Vt + lane * 40 + 16) = z;
    *(uint4*)(Vt + lane * 40 + 24) = z;
    *(uint2*)(Pb + (lane >> 2) * 40 + 16 + (lane & 3) * 4) = make_uint2(0u, 0u);
  }

  const unsigned short* src = qkv + (size_t)pos * 3072;
  #pragma unroll
  for (int i = 0; i < 6; i++){
    int c = i * 64 + lane;
    uint4 u = *(const uint4*)(src + c * 8);
    if (i < 4){
      unsigned short* mb = (c < 128) ? Qb : Kb;
      int cc = c & 127;
      *(uint4*)(mb + (cc >> 3) * 72 + (cc & 7) * 8) = u;
    } else {
      int cv = c - 256;
      int g = cv >> 3, d0 = (cv & 7) * 8;
      const unsigned short* us = (const unsigned short*)&u;
      #pragma unroll
      for (int t = 0; t < 8; t++) Vt[(d0 + t) * 40 + g] = us[t];
    }
  }
  __syncthreads();

  f32x4 s = (f32x4){0.f, 0.f, 0.f, 0.f};
  #pragma unroll
  for (int kk = 0; kk < 2; kk++){
    bf16x8 a = *(const bf16x8*)(Qb + lidx * 72 + kk * 32 + quad * 8);
    bf16x8 b = *(const bf16x8*)(Kb + lidx * 72 + kk * 32 + quad * 8);
    s = __builtin_amdgcn_mfma_f32_16x16x32_bf16(a, b, s, 0, 0, 0);
  }

  #pragma unroll
  for (int r = 0; r < 4; r++){
    float v = s[r] * 0.125f;
    float m = v;
    m = fmaxf(m, __shfl_xor(m, 1));
    m = fmaxf(m, __shfl_xor(m, 2));
    m = fmaxf(m, __shfl_xor(m, 4));
    m = fmaxf(m, __shfl_xor(m, 8));
    float e = __expf(v - m);
    float sum = e;
    sum += __shfl_xor(sum, 1);
    sum += __shfl_xor(sum, 2);
    sum += __shfl_xor(sum, 4);
    sum += __shfl_xor(sum, 8);
    float p = e / sum;
    Pb[(quad * 4 + r) * 40 + lidx] = f2bf_bits(p);
  }
  __syncthreads();

  f32x4 o[4];
  #pragma unroll
  for (int n4 = 0; n4 < 4; n4++){
    bf16x8 a = *(const bf16x8*)(Pb + lidx * 40 + quad * 8);
    bf16x8 b = *(const bf16x8*)(Vt + (n4 * 16 + lidx) * 40 + quad * 8);
    o[n4] = __builtin_amdgcn_mfma_f32_16x16x32_bf16(a, b, (f32x4){0.f,0.f,0.f,0.f}, 0, 0, 0);
  }

  #pragma unroll
  for (int n4 = 0; n4 < 4; n4++)
    #pragma unroll
    for (int r = 0; r < 4; r++)
      Qb[(quad * 4 + r) * 72 + n4 * 16 + lidx] = f2bf_bits(o[n4][r]);
  __syncthreads();

  unsigned short* dst = aout + (size_t)pos * 1024;
  #pragma unroll
  for (int t = 0; t < 2; t++){
    int j = lane * 2 + t;
    int h = j >> 3, dc = j & 7;
    uint4 u = *(const uint4*)(Qb + h * 72 + dc * 8);
    *(uint4*)(dst + j * 8) = u;
  }
}

// ---------- in-place LayerNorm over rows of 1024 fp32 ----------
__global__ __launch_bounds__(256) void k_ln(float* __restrict__ out,
                                            const float* __restrict__ gamma,
                                            const float* __restrict__ beta){
  __shared__ float red[8];
  int tid = threadIdx.x;
  float4* rowp = (float4*)(out + (size_t)blockIdx.x * 1024);
  float4 v = rowp[tid];
  float s  = v.x + v.y + v.z + v.w;
  float ss = v.x * v.x + v.y * v.y + v.z * v.z + v.w * v.w;
  #pragma unroll
  for (int off = 32; off > 0; off >>= 1){
    s  += __shfl_down(s, off);
    ss += __shfl_down(ss, off);
  }
  if ((tid & 63) == 0){ red[tid >> 6] = s; red[4 + (tid >> 6)] = ss; }
  __syncthreads();
  float S  = red[0] + red[1] + red[2] + red[3];
  float SS = red[4] + red[5] + red[6] + red[7];
  float mean = S * (1.0f / 1024.0f);
  float var  = SS * (1.0f / 1024.0f) - mean * mean;
  float rstd = rsqrtf(var + 1e-5f);
  float4 g = ((const float4*)gamma)[tid];
  float4 b = ((const float4*)beta)[tid];
  v.x = (v.x - mean) * rstd * g.x + b.x;
  v.y = (v.y - mean) * rstd * g.y + b.y;
  v.z = (v.z - mean) * rstd * g.z + b.z;
  v.w = (v.w - mean) * rstd * g.w + b.w;
  rowp[tid] = v;
}

extern "C" void kernel_launch(void* const* d_in, const int* in_sizes, int n_in,
                              void* d_out, int out_size, void* d_ws, size_t ws_size,
                              hipStream_t stream){
  const float* x     = (const float*)d_in[0];
  const float* Wq    = (const float*)d_in[1];
  const float* bq    = (const float*)d_in[2];
  const float* Wk    = (const float*)d_in[3];
  const float* bk    = (const float*)d_in[4];
  const float* Wv    = (const float*)d_in[5];
  const float* bv    = (const float*)d_in[6];
  const float* Wo    = (const float*)d_in[7];
  const float* bo    = (const float*)d_in[8];
  const float* gamma = (const float*)d_in[9];
  const float* beta  = (const float*)d_in[10];
  float* out = (float*)d_out;

  // workspace layout (bytes):
  //   [0, 6291456)            Wqkv^T bf16 (3072 x 1024)
  //   [6291456, 8388608)      Wo^T bf16  (1024 x 1024)
  //   [8388608, 75497472)     xb bf16 (32768 x 1024); reused as attn-out after GEMM1
  //   [75497472, 276824064)   qkv bf16 (32768 x 3072)
  char* ws = (char*)d_ws;
  unsigned short* Wqkv_t = (unsigned short*)ws;
  unsigned short* Wo_t   = (unsigned short*)(ws + 6291456);
  unsigned short* xb     = (unsigned short*)(ws + 8388608);
  unsigned short* qkv    = (unsigned short*)(ws + 75497472);
  unsigned short* aout   = xb;   // reuse: xb consumed by GEMM1 before attention writes

  // 1) x -> bf16
  k_convert_bf16<<<32768, 256, 0, stream>>>(x, xb, (MM * FFD) / 4);

  // 2) weight transposes (fp32 KxN -> bf16 NxK)
  dim3 tb(32, 8), tg(32, 32);
  k_transpose_bf16<<<tg, tb, 0, stream>>>(Wq, Wqkv_t,                1024, 1024);
  k_transpose_bf16<<<tg, tb, 0, stream>>>(Wk, Wqkv_t + 1024 * 1024,  1024, 1024);
  k_transpose_bf16<<<tg, tb, 0, stream>>>(Wv, Wqkv_t + 2048 * 1024,  1024, 1024);
  k_transpose_bf16<<<tg, tb, 0, stream>>>(Wo, Wo_t,                  1024, 1024);

  // 3) QKV GEMM: (32768 x 1024) @ (1024 x 3072) -> bf16  (grid 12x128 = 1536 blocks)
  k_gemm_bt<true><<<dim3(NQKV / 256, MM / 256), 512, 0, stream>>>(
      xb, Wqkv_t, bq, bk, bv, qkv, MM, NQKV, FFD);

  // 4) per-position head attention (MFMA)
  k_attention<<<MM / 4, 256, 0, stream>>>(qkv, aout);

  // 5) output GEMM: (32768 x 1024) @ (1024 x 1024) + bo -> fp32 d_out (grid 4x128 = 512)
  k_gemm_bt<false><<<dim3(FFD / 256, MM / 256), 512, 0, stream>>>(
      aout, Wo_t, bo, bo, bo, out, MM, FFD, FFD);

  // 6) LayerNorm in-place
  k_ln<<<MM, 256, 0, stream>>>(out, gamma, beta);
}